// Round 2
// baseline (1364.716 us; speedup 1.0000x reference)
//
#include <hip/hip_runtime.h>

#define NSEG 100000
#define DIM 32
#define SCAN_BLOCK 1024

// ---------- Phase 1: histogram of segment counts (int atomics) ----------
__global__ void hist_kernel(const int* __restrict__ idx, int* __restrict__ cnt, int n) {
    int i = blockIdx.x * blockDim.x + threadIdx.x;
    if (i < n) atomicAdd(&cnt[idx[i]], 1);
}

// ---------- Phase 2: two-level exclusive scan over NSEG counts ----------
__global__ void scan_block_reduce(const int* __restrict__ cnt, int* __restrict__ bsums, int nseg) {
    __shared__ int lds[SCAN_BLOCK];
    int i = blockIdx.x * SCAN_BLOCK + threadIdx.x;
    lds[threadIdx.x] = (i < nseg) ? cnt[i] : 0;
    __syncthreads();
    for (int off = SCAN_BLOCK / 2; off > 0; off >>= 1) {
        if (threadIdx.x < off) lds[threadIdx.x] += lds[threadIdx.x + off];
        __syncthreads();
    }
    if (threadIdx.x == 0) bsums[blockIdx.x] = lds[0];
}

__global__ void scan_bsums(int* __restrict__ bsums, int nb) {
    // single block of 128 threads; Hillis-Steele inclusive -> exclusive in place
    __shared__ int lds[128];
    int t = threadIdx.x;
    int v = (t < nb) ? bsums[t] : 0;
    lds[t] = v;
    __syncthreads();
    for (int off = 1; off < 128; off <<= 1) {
        int add = (t >= off) ? lds[t - off] : 0;
        __syncthreads();
        lds[t] += add;
        __syncthreads();
    }
    if (t < nb) bsums[t] = lds[t] - v;  // exclusive
}

__global__ void scan_final(const int* __restrict__ cnt, const int* __restrict__ bsums,
                           int* __restrict__ offs, int* __restrict__ cursor, int nseg) {
    __shared__ int lds[SCAN_BLOCK];
    int t = threadIdx.x;
    int i = blockIdx.x * SCAN_BLOCK + t;
    int v = (i < nseg) ? cnt[i] : 0;
    lds[t] = v;
    __syncthreads();
    for (int off = 1; off < SCAN_BLOCK; off <<= 1) {
        int add = (t >= off) ? lds[t - off] : 0;
        __syncthreads();
        lds[t] += add;
        __syncthreads();
    }
    if (i < nseg) {
        int e = bsums[blockIdx.x] + lds[t] - v;  // exclusive prefix
        offs[i] = e;
        cursor[i] = e;
    }
}

// ---------- Phase 3: scatter row ids into segment-sorted order ----------
__global__ void scatter_ids(const int* __restrict__ idx, int* __restrict__ cursor,
                            int* __restrict__ rowid, int n) {
    int i = blockIdx.x * blockDim.x + threadIdx.x;
    if (i < n) {
        int pos = atomicAdd(&cursor[idx[i]], 1);
        rowid[pos] = i;
    }
}

// ---------- Phase 4: one wave per segment, gather rows, write mean ----------
__global__ void seg_sum(const float* __restrict__ x, const int* __restrict__ rowid,
                        const int* __restrict__ offs, const int* __restrict__ cnt,
                        float* __restrict__ out, int nseg) {
    int wave = threadIdx.x >> 6;
    int lane = threadIdx.x & 63;
    int seg = blockIdx.x * (blockDim.x >> 6) + wave;
    if (seg >= nseg) return;
    int start = offs[seg];
    int count = cnt[seg];
    int col = lane & 31;   // which of the 32 columns
    int slot = lane >> 5;  // 2 rows in flight per wave
    float acc = 0.f;
    for (int j = start + slot; j < start + count; j += 2) {
        int r = rowid[j];  // 32-lane broadcast, L1-cached
        acc += x[(size_t)r * DIM + col];  // 128B fully-coalesced row read
    }
    acc += __shfl_down(acc, 32, 64);  // merge slot 1 into slot 0
    if (slot == 0) {
        out[(size_t)seg * DIM + col] = acc / fmaxf((float)count, 1.0f);
    }
}

// ---------- Fallback (ws too small): round-1 atomic version ----------
__global__ void scatter_sum_kernel(const float* __restrict__ x,
                                   const int* __restrict__ idx,
                                   float* __restrict__ sums,
                                   float* __restrict__ cnts,
                                   int n_elems) {
    int i = blockIdx.x * blockDim.x + threadIdx.x;
    if (i >= n_elems) return;
    int row = i >> 5;
    int col = i & 31;
    int seg = idx[row];
    atomicAdd(&sums[seg * DIM + col], x[i]);
    if (col == 0) atomicAdd(&cnts[seg], 1.0f);
}

__global__ void divide_kernel(float* __restrict__ out, const float* __restrict__ cnts, int n) {
    int i = blockIdx.x * blockDim.x + threadIdx.x;
    if (i >= n) return;
    float c = cnts[i >> 5];
    out[i] = out[i] / fmaxf(c, 1.0f);
}

extern "C" void kernel_launch(void* const* d_in, const int* in_sizes, int n_in,
                              void* d_out, int out_size, void* d_ws, size_t ws_size,
                              hipStream_t stream) {
    const float* x   = (const float*)d_in[0];
    const int*   idx = (const int*)d_in[1];
    float* out = (float*)d_out;

    int N = in_sizes[1];              // 4,000,000 rows
    int n_elems = in_sizes[0];        // 128,000,000 elements

    const int nb_scan = (NSEG + SCAN_BLOCK - 1) / SCAN_BLOCK;  // 98
    size_t needed = (size_t)(3 * NSEG + 128 + N) * sizeof(int);

    if (ws_size < needed) {
        // fallback: round-1 atomic path
        float* cnts = (float*)d_ws;
        hipMemsetAsync(d_out, 0, (size_t)out_size * sizeof(float), stream);
        hipMemsetAsync(d_ws, 0, (size_t)NSEG * sizeof(float), stream);
        int blocks = (n_elems + 255) / 256;
        scatter_sum_kernel<<<blocks, 256, 0, stream>>>(x, idx, out, cnts, n_elems);
        divide_kernel<<<(out_size + 255) / 256, 256, 0, stream>>>(out, cnts, out_size);
        return;
    }

    int* cnt    = (int*)d_ws;          // NSEG
    int* offs   = cnt + NSEG;          // NSEG
    int* cursor = offs + NSEG;         // NSEG
    int* bsums  = cursor + NSEG;       // 128 (padded)
    int* rowid  = bsums + 128;         // N

    hipMemsetAsync(cnt, 0, (size_t)NSEG * sizeof(int), stream);

    hist_kernel<<<(N + 255) / 256, 256, 0, stream>>>(idx, cnt, N);
    scan_block_reduce<<<nb_scan, SCAN_BLOCK, 0, stream>>>(cnt, bsums, NSEG);
    scan_bsums<<<1, 128, 0, stream>>>(bsums, nb_scan);
    scan_final<<<nb_scan, SCAN_BLOCK, 0, stream>>>(cnt, bsums, offs, cursor, NSEG);
    scatter_ids<<<(N + 255) / 256, 256, 0, stream>>>(idx, cursor, rowid, N);

    // one wave per segment, 4 waves per block
    int segblocks = (NSEG + 3) / 4;  // 25000
    seg_sum<<<segblocks, 256, 0, stream>>>(x, rowid, offs, cnt, out, NSEG);
}

// Round 3
// 1335.540 us; speedup vs baseline: 1.0218x; 1.0218x over previous
//
#include <hip/hip_runtime.h>

#define NSEG 100000
#define DIM 32
#define SPB 200            // segments per bucket
#define NBUCKET 500        // ceil(NSEG / SPB)
#define NPBLK 250          // partition blocks
#define SCAN_BLOCK 1024
#define SUM_THREADS 512

// ---------- K1: per-(chunk, bucket) count matrix, bucket-major ----------
__global__ void count_matrix(const int* __restrict__ idx, int* __restrict__ cntmat,
                             int N, int chunk) {
    __shared__ int lh[NBUCKET];
    for (int t = threadIdx.x; t < NBUCKET; t += blockDim.x) lh[t] = 0;
    __syncthreads();
    int lo = blockIdx.x * chunk;
    int hi = min(lo + chunk, N);
    for (int i = lo + threadIdx.x; i < hi; i += blockDim.x)
        atomicAdd(&lh[idx[i] / SPB], 1);
    __syncthreads();
    for (int t = threadIdx.x; t < NBUCKET; t += blockDim.x)
        cntmat[t * NPBLK + blockIdx.x] = lh[t];
}

// ---------- K2a/b/c: exclusive scan over M = NBUCKET*NPBLK ints ----------
__global__ void scan_block_reduce(const int* __restrict__ v, int* __restrict__ bsums, int M) {
    __shared__ int lds[SCAN_BLOCK];
    int i = blockIdx.x * SCAN_BLOCK + threadIdx.x;
    lds[threadIdx.x] = (i < M) ? v[i] : 0;
    __syncthreads();
    for (int off = SCAN_BLOCK / 2; off > 0; off >>= 1) {
        if (threadIdx.x < off) lds[threadIdx.x] += lds[threadIdx.x + off];
        __syncthreads();
    }
    if (threadIdx.x == 0) bsums[blockIdx.x] = lds[0];
}

__global__ void scan_bsums(int* __restrict__ bsums, int nb) {
    __shared__ int lds[128];
    int t = threadIdx.x;
    int v = (t < nb) ? bsums[t] : 0;
    lds[t] = v;
    __syncthreads();
    for (int off = 1; off < 128; off <<= 1) {
        int add = (t >= off) ? lds[t - off] : 0;
        __syncthreads();
        lds[t] += add;
        __syncthreads();
    }
    if (t < nb) bsums[t] = lds[t] - v;  // exclusive
}

__global__ void scan_final_inplace(int* __restrict__ v, const int* __restrict__ bsums, int M) {
    __shared__ int lds[SCAN_BLOCK];
    int t = threadIdx.x;
    int i = blockIdx.x * SCAN_BLOCK + t;
    int val = (i < M) ? v[i] : 0;
    lds[t] = val;
    __syncthreads();
    for (int off = 1; off < SCAN_BLOCK; off <<= 1) {
        int add = (t >= off) ? lds[t - off] : 0;
        __syncthreads();
        lds[t] += add;
        __syncthreads();
    }
    if (i < M) v[i] = bsums[blockIdx.x] + lds[t] - val;  // exclusive prefix
}

// ---------- K3: partition rows into bucket-grouped packed list ----------
// packed entry = (lseg << 24) | row   (lseg < 200 fits in 8 bits, row < 16.7M)
__global__ void partition_rows(const int* __restrict__ idx, const int* __restrict__ scan,
                               int* __restrict__ packed, int N, int chunk) {
    __shared__ int lcur[NBUCKET];
    for (int t = threadIdx.x; t < NBUCKET; t += blockDim.x)
        lcur[t] = scan[t * NPBLK + blockIdx.x];   // private (block,bucket) cursor base
    __syncthreads();
    int lo = blockIdx.x * chunk;
    int hi = min(lo + chunk, N);
    for (int i = lo + threadIdx.x; i < hi; i += blockDim.x) {
        int s = idx[i];
        int b = s / SPB;
        int ls = s - b * SPB;
        int pos = atomicAdd(&lcur[b], 1);         // LDS atomic, returns fast
        packed[pos] = (ls << 24) | i;
    }
}

// ---------- K4: one block per bucket; LDS fp32 accumulation; write means ----------
__global__ void __launch_bounds__(SUM_THREADS)
bucket_sum(const float* __restrict__ x, const int* __restrict__ packed,
           const int* __restrict__ scan, float* __restrict__ out, int N) {
    __shared__ float acc[SPB * DIM];   // 25.6 KB
    __shared__ int cl[SPB];
    for (int t = threadIdx.x; t < SPB * DIM; t += SUM_THREADS) acc[t] = 0.f;
    for (int t = threadIdx.x; t < SPB; t += SUM_THREADS) cl[t] = 0;
    __syncthreads();

    int b = blockIdx.x;
    int start = scan[b * NPBLK];
    int end = (b == NBUCKET - 1) ? N : scan[(b + 1) * NPBLK];

    int wid  = threadIdx.x >> 6;   // 0..7
    int lane = threadIdx.x & 63;
    int slot = lane >> 5;          // 0..1 : two rows per wave per k
    int col  = lane & 31;

    // each block step consumes 8 waves * 2 slots * 4 unroll = 64 entries
    for (int base = start; base < end; base += 64) {
#pragma unroll
        for (int k = 0; k < 4; ++k) {
            int j = base + wid * 8 + k * 2 + slot;
            if (j < end) {
                int p = packed[j];                 // 32-lane broadcast, L1-hot
                int row = p & 0xFFFFFF;
                int ls = ((unsigned)p) >> 24;
                float v = x[(size_t)row * DIM + col];  // 128B coalesced row read
                atomicAdd(&acc[ls * DIM + col], v);    // ds_add_f32, no return
                if (col == 0) atomicAdd(&cl[ls], 1);
            }
        }
    }
    __syncthreads();

    for (int t = threadIdx.x; t < SPB * DIM; t += SUM_THREADS) {
        int ls = t >> 5;
        int seg = b * SPB + ls;
        if (seg < NSEG)
            out[(size_t)seg * DIM + (t & 31)] = acc[t] / fmaxf((float)cl[ls], 1.0f);
    }
}

// ---------- Fallback (ws too small): round-1 atomic version ----------
__global__ void scatter_sum_kernel(const float* __restrict__ x,
                                   const int* __restrict__ idx,
                                   float* __restrict__ sums,
                                   float* __restrict__ cnts,
                                   int n_elems) {
    int i = blockIdx.x * blockDim.x + threadIdx.x;
    if (i >= n_elems) return;
    int row = i >> 5;
    int col = i & 31;
    int seg = idx[row];
    atomicAdd(&sums[seg * DIM + col], x[i]);
    if (col == 0) atomicAdd(&cnts[seg], 1.0f);
}

__global__ void divide_kernel(float* __restrict__ out, const float* __restrict__ cnts, int n) {
    int i = blockIdx.x * blockDim.x + threadIdx.x;
    if (i >= n) return;
    float c = cnts[i >> 5];
    out[i] = out[i] / fmaxf(c, 1.0f);
}

extern "C" void kernel_launch(void* const* d_in, const int* in_sizes, int n_in,
                              void* d_out, int out_size, void* d_ws, size_t ws_size,
                              hipStream_t stream) {
    const float* x   = (const float*)d_in[0];
    const int*   idx = (const int*)d_in[1];
    float* out = (float*)d_out;

    int N = in_sizes[1];              // 4,000,000 rows
    int n_elems = in_sizes[0];        // 128,000,000 elements

    const int M = NBUCKET * NPBLK;    // 125,000
    const int nb_scan = (M + SCAN_BLOCK - 1) / SCAN_BLOCK;  // 123
    size_t needed = ((size_t)M + 128 + (size_t)N) * sizeof(int);  // ~16.5 MB

    if (ws_size < needed) {
        float* cnts = (float*)d_ws;
        hipMemsetAsync(d_out, 0, (size_t)out_size * sizeof(float), stream);
        hipMemsetAsync(d_ws, 0, (size_t)NSEG * sizeof(float), stream);
        int blocks = (n_elems + 255) / 256;
        scatter_sum_kernel<<<blocks, 256, 0, stream>>>(x, idx, out, cnts, n_elems);
        divide_kernel<<<(out_size + 255) / 256, 256, 0, stream>>>(out, cnts, out_size);
        return;
    }

    int* cntmat = (int*)d_ws;         // M ints (count matrix, then its exclusive scan)
    int* bsums  = cntmat + M;         // 128 ints
    int* packed = bsums + 128;        // N ints

    int chunk = (N + NPBLK - 1) / NPBLK;   // 16000

    count_matrix<<<NPBLK, 256, 0, stream>>>(idx, cntmat, N, chunk);
    scan_block_reduce<<<nb_scan, SCAN_BLOCK, 0, stream>>>(cntmat, bsums, M);
    scan_bsums<<<1, 128, 0, stream>>>(bsums, nb_scan);
    scan_final_inplace<<<nb_scan, SCAN_BLOCK, 0, stream>>>(cntmat, bsums, M);
    partition_rows<<<NPBLK, 256, 0, stream>>>(idx, cntmat, packed, N, chunk);
    bucket_sum<<<NBUCKET, SUM_THREADS, 0, stream>>>(x, packed, cntmat, out, N);
}